// Round 6
// baseline (193.817 us; speedup 1.0000x reference)
//
#include <hip/hip_runtime.h>

#define B_SZ 128
#define MCHK 288
#define NVAR 576
#define KINFO 288
#define NITER 5
#define CAP 40      // max edges per check row (mean 11.5, 8.5 sigma headroom)
#define TPB 1024
#define NWAVES (TPB / 64)        // 16
#define RPW (MCHK / NWAVES)      // 18 rows per wave (exact)

// ---------------------------------------------------------------------------
// Single fused kernel, one 1024-thread block per batch element. No workspace,
// no device globals, no grid barrier (round-5 lesson: barrier+half-idle tail
// costs more than a launch).
//  Phase A: per-block H scan (verified emission order) -> LDS stage + rcnt.
//  Edge regs: wave w owns rows w*18..w*18+17; lane j owns edge j of each
//           row. v/w_cv/Ml live in REGISTERS, statically indexed (full
//           unroll). No ev/tld/Prow LDS arrays, no compaction scan at all.
//  Phase C: 5 iterations, ONE fused pass each: per-edge tanh -> row product
//           via 6 shfl_xor multiplies (reassociation OK: threshold 2e-2,
//           we sit at the 4.88e-4 bf16 floor) -> c2v + gated update ->
//           atomicAdd scatter into S_acc. S double-buffered; 2 barriers/iter.
//  Epilogue: deferred |post| reductions (unchanged from round 3).
// ---------------------------------------------------------------------------
__global__ __launch_bounds__(TPB) void decode(
    const float* __restrict__ H,
    const float* __restrict__ inp,   const float* __restrict__ sigma2,
    const float* __restrict__ ipond, const float* __restrict__ opond,
    const float* __restrict__ skipp, const float* __restrict__ wcv,
    const float* __restrict__ gatel, float* __restrict__ out) {

    __shared__ unsigned short stage[MCHK * CAP];   // 23040 B, persists
    __shared__ float xln[NVAR];                    // normalized LLRs
    __shared__ float Sb[2][NVAR];                  // S double buffer
    __shared__ int   rcnt[MCHK];
    __shared__ float red[16];                      // initial |llr| reduction
    __shared__ float redT[NITER][16];              // deferred |post_t| reductions

    const int b    = blockIdx.x;
    const int tid  = threadIdx.x;
    const int wid  = tid >> 6;
    const int lane = tid & 63;

    const float sig  = sigma2[b];
    const float gate = 1.0f / (1.0f + __expf(-gatel[0]));
    const float gbar = 1.0f - gate;
    const float skip = skipp[0];

    float ipl[NITER], opl[NITER];
    #pragma unroll
    for (int t = 0; t < NITER; ++t) { ipl[t] = ipond[t]; opl[t] = opond[t]; }

    // ---- LLR load + |llr| wave reduction (red covered by Phase-A barrier) ----
    float l = 0.0f;
    if (tid < NVAR) l = -4.0f * inp[(size_t)b * NVAR + tid] / sig;
    float al = (tid < NVAR) ? fabsf(l) : 0.0f;
    #pragma unroll
    for (int o = 32; o; o >>= 1) al += __shfl_down(al, o, 64);
    if (lane == 0) red[wid] = al;

    // ---- Phase A: per-block H scan -> stage/rcnt (identical emission) ----
    {
        const float* Hb = H + (size_t)b * (MCHK * NVAR);
        const int m0 = wid * RPW;
        const float* hr = Hb + (size_t)m0 * NVAR;
        float4 a = ((const float4*)hr)[lane];      // cols 4*lane..4*lane+3
        float4 q = ((const float4*)hr)[64 + lane]; // cols 256+4*lane..
        float  c = hr[512 + lane];                 // col 512+lane
        #pragma unroll
        for (int i = 0; i < RPW; ++i) {
            const int m = m0 + i;
            float4 na = a, nq = q; float nc = c;   // 1-deep prefetch
            if (i < RPW - 1) {
                const float* hn = Hb + (size_t)(m + 1) * NVAR;
                na = ((const float4*)hn)[lane];
                nq = ((const float4*)hn)[64 + lane];
                nc = hn[512 + lane];
            }
            int cnt = (a.x!=0.f)+(a.y!=0.f)+(a.z!=0.f)+(a.w!=0.f)
                    + (q.x!=0.f)+(q.y!=0.f)+(q.z!=0.f)+(q.w!=0.f) + (c!=0.f);
            int pre = cnt;
            #pragma unroll
            for (int o = 1; o < 64; o <<= 1) {
                int n = __shfl_up(pre, o, 64);
                if (lane >= o) pre += n;
            }
            int p = pre - cnt;                     // exclusive offset in row
            unsigned short* dst = stage + m * CAP;
            int base = lane * 4;
            if (a.x!=0.f) { if (p<CAP) dst[p] = (unsigned short)(base    ); p++; }
            if (a.y!=0.f) { if (p<CAP) dst[p] = (unsigned short)(base + 1); p++; }
            if (a.z!=0.f) { if (p<CAP) dst[p] = (unsigned short)(base + 2); p++; }
            if (a.w!=0.f) { if (p<CAP) dst[p] = (unsigned short)(base + 3); p++; }
            if (q.x!=0.f) { if (p<CAP) dst[p] = (unsigned short)(256 + base    ); p++; }
            if (q.y!=0.f) { if (p<CAP) dst[p] = (unsigned short)(256 + base + 1); p++; }
            if (q.z!=0.f) { if (p<CAP) dst[p] = (unsigned short)(256 + base + 2); p++; }
            if (q.w!=0.f) { if (p<CAP) dst[p] = (unsigned short)(256 + base + 3); p++; }
            if (c!=0.f)   { if (p<CAP) dst[p] = (unsigned short)(512 + lane);     p++; }
            if (lane == 63) rcnt[m] = (pre > CAP) ? CAP : pre;
            a = na; q = nq; c = nc;
        }
    }
    __syncthreads();

    // ---- normalization scale (same fixed order), xln, zero S buffers ----
    {
        float s = 0.0f;
        #pragma unroll
        for (int i = 0; i < 16; ++i) s += red[i];
        const float sc = (float)NVAR / s;          // 1 / mean|llr|
        if (tid < NVAR) {
            xln[tid]   = l * sc;
            Sb[0][tid] = 0.0f;
            Sb[1][tid] = 0.0f;
        }
    }

    // ---- per-lane edge state into registers (lane j = edge j of row) ----
    int   vr[RPW];  float wr[RPW], Ml[RPW];  int cntr[RPW];
    #pragma unroll
    for (int r2 = 0; r2 < RPW; ++r2) {
        const int m = wid * RPW + r2;
        const int c = rcnt[m];
        cntr[r2] = c;
        int v = 0; float w = 0.0f;
        if (lane < c) {
            v = stage[m * CAP + lane];
            w = wcv[m * NVAR + v];
        }
        vr[r2] = v; wr[r2] = w; Ml[r2] = 0.0f;
    }
    __syncthreads();           // xln + S zeroing visible

    // ---- Phase C: 5 iterations, fused pass, 2 barriers each ----
    float p[NITER];
    #pragma unroll
    for (int t = 0; t < NITER; ++t) p[t] = 0.0f;

    #pragma unroll
    for (int t = 0; t < NITER; ++t) {
        const float pt = ipl[t];
        float* const sr = Sb[t & 1];           // read: S_{t-1}
        float* const sa = Sb[(t + 1) & 1];     // accumulate: S_t (zeroed)

        #pragma unroll
        for (int r2 = 0; r2 < RPW; ++r2) {
            const bool act = (lane < cntr[r2]);
            const int  v   = vr[r2];
            float V = 0.0f;
            if (act) V = fmaf(pt, xln[v], sr[v]) - Ml[r2];
            V = fminf(15.0f, fmaxf(-15.0f, V));
            float ex = __expf(V);
            float te = (ex - 1.0f) * __builtin_amdgcn_rcpf(ex + 1.0f);
            float x  = 0.5f * V, x2 = x * x;
            float tp = x * fmaf(x2, fmaf(x2, fmaf(x2, -0.05396825f, 0.13333333f),
                                         -0.33333333f), 1.0f);
            const float tv = (fabsf(V) < 0.5f) ? tp : te;
            // full-wave product; inactive lanes contribute exactly 1.0f
            float P = act ? tv : 1.0f;
            P *= __shfl_xor(P,  1, 64);
            P *= __shfl_xor(P,  2, 64);
            P *= __shfl_xor(P,  4, 64);
            P *= __shfl_xor(P,  8, 64);
            P *= __shfl_xor(P, 16, 64);
            P *= __shfl_xor(P, 32, 64);
            if (act) {
                const float ts = (fabsf(tv) < 1e-7f)
                               ? ((tv >= 0.0f) ? 1e-7f : -1e-7f) : tv;
                float r = P * __builtin_amdgcn_rcpf(ts);
                r = fminf(1.0f - 1e-6f, fmaxf(-1.0f + 1e-6f, r));
                const float Mn = __logf((1.0f + r) * __builtin_amdgcn_rcpf(1.0f - r))
                               * wr[r2];
                const float Mo = fmaf(gate, Mn, gbar * Ml[r2]);
                Ml[r2] = Mo;
                atomicAdd(&sa[v], Mo);
            }
        }
        __syncthreads();       // sa = S_t complete

        if (tid < NVAR) {
            p[t] = fmaf(pt, xln[tid], sa[tid]);  // posterior_t
            sr[tid] = 0.0f;                      // becomes next accumulator
        }
        __syncthreads();
    }

    // ---- deferred |post_t| reductions (fixed order per t) ----
    #pragma unroll
    for (int t = 0; t < NITER; ++t) {
        float ap = (tid < NVAR) ? fabsf(p[t]) : 0.0f;
        #pragma unroll
        for (int o = 32; o; o >>= 1) ap += __shfl_down(ap, o, 64);
        if (lane == 0) redT[t][wid] = ap;
    }
    __syncthreads();

    // ---- pooled accumulation + output ----
    if (tid < KINFO) {
        float pooled = 0.0f;
        #pragma unroll
        for (int t = 0; t < NITER; ++t) {
            float s2 = 0.0f;
            #pragma unroll
            for (int i = 0; i < 16; ++i) s2 += redT[t][i];
            pooled += opl[t] * p[t] * ((float)NVAR / s2);
        }
        float o = pooled * (1.0f / NITER) + skip * xln[tid];
        out[(size_t)b * KINFO + tid] = 1.0f / (1.0f + __expf(o));
    }
}

extern "C" void kernel_launch(void* const* d_in, const int* in_sizes, int n_in,
                              void* d_out, int out_size, void* d_ws, size_t ws_size,
                              hipStream_t stream) {
    const float* inp    = (const float*)d_in[0];
    const float* H      = (const float*)d_in[1];
    const float* sigma2 = (const float*)d_in[2];
    const float* ipond  = (const float*)d_in[3];
    const float* opond  = (const float*)d_in[4];
    const float* skipp  = (const float*)d_in[5];
    const float* wcv    = (const float*)d_in[6];
    const float* gatel  = (const float*)d_in[7];
    float* out = (float*)d_out;

    decode<<<B_SZ, TPB, 0, stream>>>(H, inp, sigma2, ipond, opond, skipp,
                                     wcv, gatel, out);
}

// Round 7
// 169.929 us; speedup vs baseline: 1.1406x; 1.1406x over previous
//
#include <hip/hip_runtime.h>

#define B_SZ 128
#define MCHK 288
#define NVAR 576
#define KINFO 288
#define NITER 5
#define CAP 40      // max edges per check row (mean 11.5, 8.5 sigma headroom)
#define LCAP 3712   // max edges per batch element (mean 3318, 6.9 sigma)
#define TPB 1024
#define EPT 4       // max edges per thread: LCAP <= EPT*TPB

// ---------------------------------------------------------------------------
// Single fused kernel, one 1024-thread block per batch element (round-2
// structure, which measured 65us — the best kernel time so far), with two
// verified deltas grafted in:
//   (1) deferred posterior normalization (round 3, passed bitwise): p[t] in
//       registers, all |post| reductions after the loop -> 3 barriers/iter.
//   (2) rowprod remapped to threads 736..1023 so it overlaps the posterior
//       capture + S zeroing on threads 0..575 (disjoint ranges; FP order
//       of every sum/product unchanged -> bitwise-identical results).
// Phase A/B and pass1/pass2 bodies are byte-identical to round 2.
// ---------------------------------------------------------------------------
__global__ __launch_bounds__(TPB) void decode(
    const float* __restrict__ inp,   const float* __restrict__ H,
    const float* __restrict__ sigma2,
    const float* __restrict__ ipond, const float* __restrict__ opond,
    const float* __restrict__ skipp, const float* __restrict__ wcv,
    const float* __restrict__ gatel, float* __restrict__ out) {

    // tld (per-edge tanh, LCAP*4 = 14848 B) aliases the Phase-A ushort
    // staging buffer (MCHK*CAP*2 = 23040 B); union sized to the larger.
    __shared__ __align__(16) float MT[(MCHK * CAP) / 2];   // 23040 B
    __shared__ unsigned int ev[LCAP];    // per-edge (m<<16)|v
    __shared__ float xln[NVAR];          // normalized LLRs
    __shared__ float S[NVAR];            // per-variable message sum
    __shared__ float Prow[MCHK];         // per-row tanh product
    __shared__ int   rcnt[MCHK];
    __shared__ int   roff[MCHK];
    __shared__ float red[16];            // initial |llr| reduction
    __shared__ float redT[NITER][16];    // deferred |post_t| reductions
    __shared__ int   wsumI[16];
    __shared__ int   EtotS;

    float* const tld = MT;
    unsigned short* const stage = (unsigned short*)MT;   // [MCHK][CAP]

    const int b    = blockIdx.x;
    const int tid  = threadIdx.x;
    const int wid  = tid >> 6;
    const int lane = tid & 63;

    const float sig  = sigma2[b];
    const float gate = 1.0f / (1.0f + __expf(-gatel[0]));
    const float gbar = 1.0f - gate;
    const float skip = skipp[0];

    float ipl[NITER], opl[NITER];
    #pragma unroll
    for (int t = 0; t < NITER; ++t) { ipl[t] = ipond[t]; opl[t] = opond[t]; }

    // ---- LLR load + |llr| wave reduction (red covered by Phase-A barrier) ----
    float l = 0.0f;
    if (tid < NVAR) l = -4.0f * inp[(size_t)b * NVAR + tid] / sig;
    float al = (tid < NVAR) ? fabsf(l) : 0.0f;
    #pragma unroll
    for (int o = 32; o; o >>= 1) al += __shfl_down(al, o, 64);
    if (lane == 0) red[wid] = al;

    // ---- Phase A: H scan -> staged per-row edge lists in LDS ----
    {
        const float* Hb = H + (size_t)b * (MCHK * NVAR);
        const float* hr0 = Hb + (size_t)wid * NVAR;
        float4 a  = ((const float4*)hr0)[lane];       // cols 4*lane..
        float4 bq = ((const float4*)hr0)[64 + lane];  // cols 256+4*lane..
        float  hc = hr0[512 + lane];                  // col 512+lane
        for (int m = wid; m < MCHK; m += 16) {
            // prefetch next row before doing this row's scan/store work
            const int mn = m + 16;
            float4 na = a, nbq = bq; float nhc = hc;
            if (mn < MCHK) {
                const float* hr = Hb + (size_t)mn * NVAR;
                na  = ((const float4*)hr)[lane];
                nbq = ((const float4*)hr)[64 + lane];
                nhc = hr[512 + lane];
            }
            int cnt = (a.x!=0.f)+(a.y!=0.f)+(a.z!=0.f)+(a.w!=0.f)
                    + (bq.x!=0.f)+(bq.y!=0.f)+(bq.z!=0.f)+(bq.w!=0.f) + (hc!=0.f);
            int pre = cnt;
            #pragma unroll
            for (int o = 1; o < 64; o <<= 1) {
                int n = __shfl_up(pre, o, 64);
                if (lane >= o) pre += n;
            }
            int p = pre - cnt;                       // exclusive offset in row
            unsigned short* dst = stage + m * CAP;
            int base = lane * 4;
            if (a.x!=0.f)  { if (p<CAP) dst[p] = (unsigned short)(base    ); p++; }
            if (a.y!=0.f)  { if (p<CAP) dst[p] = (unsigned short)(base + 1); p++; }
            if (a.z!=0.f)  { if (p<CAP) dst[p] = (unsigned short)(base + 2); p++; }
            if (a.w!=0.f)  { if (p<CAP) dst[p] = (unsigned short)(base + 3); p++; }
            if (bq.x!=0.f) { if (p<CAP) dst[p] = (unsigned short)(256 + base    ); p++; }
            if (bq.y!=0.f) { if (p<CAP) dst[p] = (unsigned short)(256 + base + 1); p++; }
            if (bq.z!=0.f) { if (p<CAP) dst[p] = (unsigned short)(256 + base + 2); p++; }
            if (bq.w!=0.f) { if (p<CAP) dst[p] = (unsigned short)(256 + base + 3); p++; }
            if (hc!=0.f)   { if (p<CAP) dst[p] = (unsigned short)(512 + lane);     p++; }
            if (lane == 63) rcnt[m] = (pre > CAP) ? CAP : pre;
            a = na; bq = nbq; hc = nhc;
        }
    }
    __syncthreads();

    // ---- Phase B: shfl scan of row counts (waves 0..4 cover 320 slots) ----
    int myc = 0, incl = 0;
    if (tid < 320) {
        myc  = (tid < MCHK) ? rcnt[tid] : 0;
        incl = myc;
        #pragma unroll
        for (int o = 1; o < 64; o <<= 1) {
            int n = __shfl_up(incl, o, 64);
            if (lane >= o) incl += n;
        }
        if (lane == 63) wsumI[wid] = incl;
    }
    __syncthreads();
    if (tid < MCHK) {
        int o = incl - myc;                      // exclusive within wave
        #pragma unroll
        for (int w = 0; w < 4; ++w) if (w < wid) o += wsumI[w];
        int c = myc;
        if (o >= LCAP)         { o = 0; c = 0; }           // defensive
        else if (o + c > LCAP) { c = LCAP - o; }           // defensive
        roff[tid] = o; rcnt[tid] = c;
        const unsigned short* sg = stage + tid * CAP;
        for (int j = 0; j < c; ++j)
            ev[o + j] = ((unsigned)tid << 16) | (unsigned)sg[j];
    }
    if (tid < NVAR) S[tid] = 0.0f;
    if (tid == 0) {
        int e = wsumI[0] + wsumI[1] + wsumI[2] + wsumI[3] + wsumI[4];
        EtotS = (e > LCAP) ? LCAP : e;
    }
    __syncthreads();           // stage reads done; tld may now clobber it
    const int E = EtotS;

    // ---- B2: normalization scale (same summation order -> bit-identical),
    //      xln write, per-thread edge state into registers ----
    {
        float s = 0.0f;
        #pragma unroll
        for (int i = 0; i < 16; ++i) s += red[i];
        const float sc = (float)NVAR / s;        // 1 / mean|llr|
        if (tid < NVAR) xln[tid] = l * sc;
    }
    unsigned evr[EPT]; float wre[EPT], Ml[EPT], tre[EPT];
    #pragma unroll
    for (int k = 0; k < EPT; ++k) {
        evr[k] = 0u; wre[k] = 0.0f; Ml[k] = 0.0f; tre[k] = 0.0f;
        const int e = tid + k * TPB;
        if (e < E) {
            const unsigned pk = ev[e];
            evr[k] = pk;
            wre[k] = wcv[(pk >> 16) * NVAR + (pk & 0xFFFFu)];
        }
    }
    __syncthreads();           // xln visible to all

    // ---- Phase C: 5 BP iterations, 3 barriers each, deferred norm ----
    float p[NITER];            // post_t, static-indexed via full unroll
    #pragma unroll
    for (int t = 0; t < NITER; ++t) p[t] = 0.0f;

    #pragma unroll
    for (int t = 0; t < NITER; ++t) {
        const float pt = ipl[t];

        // pass 1: per-edge tanh(0.5*clip(V)); t kept in a register for pass2
        #pragma unroll
        for (int k = 0; k < EPT; ++k) {
            const int e = tid + k * TPB;
            if (e < E) {
                const int v = (int)(evr[k] & 0xFFFFu);
                float V = fmaf(pt, xln[v], S[v]) - Ml[k];
                V = fminf(15.0f, fmaxf(-15.0f, V));
                float ex = __expf(V);
                float te = (ex - 1.0f) * __builtin_amdgcn_rcpf(ex + 1.0f);
                float x  = 0.5f * V, x2 = x * x;
                float tp = x * fmaf(x2, fmaf(x2, fmaf(x2, -0.05396825f, 0.13333333f),
                                             -0.33333333f), 1.0f);
                const float tv = (fabsf(V) < 0.5f) ? tp : te;
                tre[k] = tv;
                tld[e] = tv;
            }
        }
        __syncthreads();

        // OVERLAPPED middle phase:
        //   threads 736..1023: row products (multiply order unchanged)
        //   threads   0..575 : capture post_{t-1} (S still = S_{t-1}), zero S
        {
            const int rm = tid - 736;            // 0..287 on the top waves
            if (rm >= 0) {
                const int c = rcnt[rm], o = roff[rm];
                float P = 1.0f;
                if (c > 0) {
                    float cur = tld[o];
                    for (int j = 1; j < c; ++j) {
                        const float nx = tld[o + j];
                        P *= cur;
                        cur = nx;
                    }
                    P *= cur;
                }
                Prow[rm] = P;
            }
        }
        if (tid < NVAR) {
            if (t > 0) p[t - 1] = fmaf(ipl[t - 1], xln[tid], S[tid]);
            S[tid] = 0.0f;
        }
        __syncthreads();

        // pass 2: c2v message from registers + gated update + scatter
        #pragma unroll
        for (int k = 0; k < EPT; ++k) {
            const int e = tid + k * TPB;
            if (e < E) {
                const unsigned pk = evr[k];
                const int v = (int)(pk & 0xFFFFu);
                const int m = (int)(pk >> 16);
                const float tj = tre[k];
                const float ts = (fabsf(tj) < 1e-7f) ? ((tj >= 0.0f) ? 1e-7f : -1e-7f) : tj;
                float r = Prow[m] * __builtin_amdgcn_rcpf(ts);
                r = fminf(1.0f - 1e-6f, fmaxf(-1.0f + 1e-6f, r));
                const float Mn = __logf((1.0f + r) * __builtin_amdgcn_rcpf(1.0f - r)) * wre[k];
                const float Mo = fmaf(gate, Mn, gbar * Ml[k]);
                Ml[k] = Mo;
                atomicAdd(&S[v], Mo);
            }
        }
        __syncthreads();
        // no norm phase: deferred to after the loop
    }

    // final posterior (S holds S_{NITER-1} after the last barrier)
    if (tid < NVAR) p[NITER - 1] = fmaf(ipl[NITER - 1], xln[tid], S[tid]);

    // ---- deferred reductions: identical shfl/red order per t ----
    #pragma unroll
    for (int t = 0; t < NITER; ++t) {
        float ap = (tid < NVAR) ? fabsf(p[t]) : 0.0f;
        #pragma unroll
        for (int o = 32; o; o >>= 1) ap += __shfl_down(ap, o, 64);
        if (lane == 0) redT[t][wid] = ap;
    }
    __syncthreads();

    // ---- pooled accumulation in t order (bitwise-identical) + output ----
    if (tid < KINFO) {
        float pooled = 0.0f;
        #pragma unroll
        for (int t = 0; t < NITER; ++t) {
            float s2 = 0.0f;
            #pragma unroll
            for (int i = 0; i < 16; ++i) s2 += redT[t][i];
            pooled += opl[t] * p[t] * ((float)NVAR / s2);
        }
        float o = pooled * (1.0f / NITER) + skip * xln[tid];
        out[(size_t)b * KINFO + tid] = 1.0f / (1.0f + __expf(o));
    }
}

extern "C" void kernel_launch(void* const* d_in, const int* in_sizes, int n_in,
                              void* d_out, int out_size, void* d_ws, size_t ws_size,
                              hipStream_t stream) {
    const float* inp    = (const float*)d_in[0];
    const float* H      = (const float*)d_in[1];
    const float* sigma2 = (const float*)d_in[2];
    const float* ipond  = (const float*)d_in[3];
    const float* opond  = (const float*)d_in[4];
    const float* skipp  = (const float*)d_in[5];
    const float* wcv    = (const float*)d_in[6];
    const float* gatel  = (const float*)d_in[7];
    float* out = (float*)d_out;

    decode<<<B_SZ, TPB, 0, stream>>>(inp, H, sigma2, ipond, opond, skipp,
                                     wcv, gatel, out);
}